// Round 12
// baseline (272.676 us; speedup 1.0000x reference)
//
#include <hip/hip_runtime.h>
#include <math.h>

// AttnBlock: GroupNorm(32) -> q,k,v 1x1 -> spatial attention -> proj -> resid.
// Round 21: attn = 8 waves x 32 q/wave = 256 q/block @ launch_bounds(512,1)
// -> 2 waves/SIMD with the FULL 256-reg budget (the untested cell of the
// R6/R7 matrix: 32q needs ~220 regs incl. accO[16][2]; fits 256, spilled at
// 128). Each K/V ds_read feeds 2 MFMAs -> tile-visits/CU halve (32->16),
// per-CU LDS traffic 16MB -> 8MB (the measured 85% floor). sn-pipeline
// dropped (register relief); K/V double-buffered, ONE barrier/tile: at
// barrier(t) the DMAs into buf[t&1] are drained and buf[(t+1)&1]'s last
// readers (tile t-1) already finished -> DMA K/V(t+1) overlaps all of
// tile t's compute. KSPLIT=4 keeps grid=256=1 block/CU (proj merges 4).

#define BB 4
#define CCH 256
#define NSP 4096
#define EPSV 1e-5f
#define ATTN_SCALE 0.0625f  // 256^-0.5
#define RSQRT2 0.70710678118654752440f
#define KSPLIT 4
#define TILES_PER_PART 16   // 4096 / 64 / KSPLIT

typedef __attribute__((ext_vector_type(8))) short bf16x8;
typedef __attribute__((ext_vector_type(4))) float f32x4;

typedef __attribute__((address_space(1))) void gvoid;
typedef __attribute__((address_space(3))) void lvoid;
__device__ __forceinline__ void dma16(const void* g, void* l) {
  __builtin_amdgcn_global_load_lds((gvoid*)g, (lvoid*)l, 16, 0, 0);
}

__device__ __forceinline__ short f2bf(float f) {
  union { float f; unsigned u; } a; a.f = f;
  unsigned r = a.u + 0x7fffu + ((a.u >> 16) & 1u);  // RTN-even
  return (short)(r >> 16);
}
__device__ __forceinline__ float bf2f(short s) {
  union { unsigned u; float f; } a;
  a.u = ((unsigned)(unsigned short)s) << 16;
  return a.f;
}
__device__ __forceinline__ unsigned cvt_pk_bf16(float lo, float hi) {
  unsigned r;
  asm("v_cvt_pk_bf16_f32 %0, %1, %2" : "=v"(r) : "v"(lo), "v"(hi));
  return r;
}

// ---- prep_all: GN partial stats (blocks 0..255) + W transpose (256..319) ---
__global__ __launch_bounds__(256) void prep_all(
    const float* __restrict__ x,
    const float* __restrict__ Wq, const float* __restrict__ Wk,
    const float* __restrict__ Wv, const float* __restrict__ Wp,
    float* __restrict__ stats, short* __restrict__ wts) {
  __shared__ float T[64][65];
  int bid = blockIdx.x;
  int tid = threadIdx.x;
  if (bid < 256) {
    int b = bid >> 6, g = (bid >> 1) & 31, h = bid & 1;
    size_t base = ((size_t)b * CCH + (size_t)g * 8 + (size_t)h * 4) * NSP;
    const float4* xv = (const float4*)(x + base);
    float s = 0.f, ss = 0.f;
    for (int i = tid; i < 4096; i += 256) {
      float4 v = xv[i];
      s += (v.x + v.y) + (v.z + v.w);
      ss += (v.x * v.x + v.y * v.y) + (v.z * v.z + v.w * v.w);
    }
#pragma unroll
    for (int off = 32; off > 0; off >>= 1) {
      s += __shfl_down(s, off, 64);
      ss += __shfl_down(ss, off, 64);
    }
    int wv = tid >> 6;
    if ((tid & 63) == 0) { T[0][wv] = s; T[0][4 + wv] = ss; }
    __syncthreads();
    if (tid == 0) {
      float S = T[0][0] + T[0][1] + T[0][2] + T[0][3];
      float SS = T[0][4] + T[0][5] + T[0][6] + T[0][7];
      stats[((b * 32 + g) * 2 + h) * 2 + 0] = S;
      stats[((b * 32 + g) * 2 + h) * 2 + 1] = SS;
    }
  } else {
    int wid = bid - 256;
    int c0 = (wid & 3) * 64, d0 = ((wid >> 2) & 3) * 64;
    int wz = wid >> 4;
    const float* W = (wz == 0) ? Wq : (wz == 1) ? Wk : (wz == 2) ? Wv : Wp;
    short* wt = wts + (size_t)wz * CCH * CCH;
#pragma unroll
    for (int i = 0; i < 16; ++i) {
      int idx = tid + 256 * i;
      int row = idx >> 6, col = idx & 63;
      T[row][col] = W[(size_t)(c0 + row) * CCH + d0 + col];
    }
    __syncthreads();
#pragma unroll
    for (int i = 0; i < 16; ++i) {
      int idx = tid + 256 * i;
      int dr = idx >> 6, cc = idx & 63;
      wt[(size_t)(d0 + dr) * CCH + c0 + cc] = f2bf(T[cc][dr]);
    }
  }
}

// ------- qkvg: fused GN-apply + q,k,v projections via bf16 MFMA -----------
// n-block = 32, grid 512 = 2 blocks/CU. 256 threads / 4 waves:
// wave w: wr = w&1 (n-group of 16), h = w>>1 (d-half of 128).
__global__ __launch_bounds__(256) void qkvg_kernel(
    const float* __restrict__ x, const float* __restrict__ stats,
    const float* __restrict__ gw, const float* __restrict__ gb,
    const short* __restrict__ wqt, const short* __restrict__ wkt,
    const short* __restrict__ wvt,
    const float* __restrict__ bq, const float* __restrict__ bk,
    const float* __restrict__ bv,
    short* __restrict__ qo, short* __restrict__ ko, short* __restrict__ vo) {
  __shared__ __align__(16) unsigned char smem[26880];
  float* aco = (float*)smem;                      // 256 f32
  float* bco = aco + 256;                         // 256 f32
  float (*Ts)[33] = (float(*)[33])(smem + 2048);  // 64 x 33 fp32 (8448 B)
  short* Hs = (short*)(smem + 10496);             // [32 n][256 c] swizzled
  short* Fo = (short*)(smem + 2048);              // epilogue [32 n][264] bf16

  int bx = blockIdx.x;
  int b = bx & 3, n0 = (bx >> 2) * 32;
  int tid = threadIdx.x;
  {  // per-channel scale/shift (combine 2 GN partials)
    int g = tid >> 3;
    const float* sp = stats + (size_t)(b * 32 + g) * 4;
    float S = sp[0] + sp[2], SS = sp[1] + sp[3];
    float mean = S * (1.f / 32768.f);
    float var = SS * (1.f / 32768.f) - mean * mean;
    float rstd = rsqrtf(var + EPSV);
    float a = gw[tid] * rstd;
    aco[tid] = a;
    bco[tid] = gb[tid] - mean * a;
  }
  __syncthreads();
  const float* xb = x + (size_t)b * CCH * NSP;
  // ---- 4 passes: load x chunk (64c x 32n), normalize, transpose -> Hs ----
  for (int p = 0; p < 4; ++p) {
    int c0 = p * 64;
#pragma unroll
    for (int i = 0; i < 2; ++i) {
      int crow = (tid >> 3) + i * 32;
      int c = c0 + crow;
      float4 v = *(const float4*)&xb[(size_t)c * NSP + n0 + (tid & 7) * 4];
      float a = aco[c], bb = bco[c];
      v.x = v.x * a + bb; v.y = v.y * a + bb;
      v.z = v.z * a + bb; v.w = v.w * a + bb;
      *(float4*)&Ts[crow][(tid & 7) * 4] = v;   // Ts[c_local][n_local]
    }
    __syncthreads();
    {
      int n = tid >> 3, seg = tid & 7;
      int cb = seg * 8;
      bf16x8 r;
#pragma unroll
      for (int j = 0; j < 8; ++j) r[j] = f2bf(Ts[cb + j][n]);
      int chunk = p * 8 + seg;
      *(bf16x8*)(Hs + n * 256 + ((chunk ^ (n & 7)) * 8)) = r;
    }
    __syncthreads();
  }
  // ---- extract B-frags (rows = this wave's 16 n; shared across h) ----
  int w = tid >> 6, lane = tid & 63, quad = lane >> 4, l16 = lane & 15;
  int wr = w & 1, h = w >> 1;  // n-group, d-half
  bf16x8 a_h[8];
  {
    int row = wr * 16 + l16;
#pragma unroll
    for (int kc = 0; kc < 8; ++kc)
      a_h[kc] = *(bf16x8*)(Hs + row * 256 + (((kc * 4 + quad) ^ (row & 7)) * 8));
  }
  __syncthreads();  // all waves extracted; smem reusable as Fo
  // ---- 3 projections; wave handles d in [h*128, h*128+128) ----
  for (int op = 0; op < 3; ++op) {
    const short* wt = (op == 0) ? wqt : (op == 1) ? wkt : wvt;
    const float* bias = (op == 0) ? bq : (op == 1) ? bk : bv;
    f32x4 acc[8];
#pragma unroll
    for (int mb = 0; mb < 8; ++mb) acc[mb] = (f32x4){0.f, 0.f, 0.f, 0.f};
#pragma unroll 4
    for (int mb = 0; mb < 8; ++mb) {
      const short* wp = wt + (size_t)((h * 8 + mb) * 16 + l16) * CCH + quad * 8;
#pragma unroll
      for (int kc = 0; kc < 8; ++kc) {
        bf16x8 af = *(const bf16x8*)(wp + kc * 32);
        acc[mb] = __builtin_amdgcn_mfma_f32_16x16x32_bf16(af, a_h[kc], acc[mb], 0, 0, 0);
      }
    }
    int n = n0 + wr * 16 + l16;
    if (op == 2) {  // v: [c][n-permuted] scalar stores (global-n formulas)
      short* ob = vo + (size_t)b * CCH * NSP;
      int mm = n & 63, m0_ = n & ~63;
      int mb_ = mm >> 4, qq = (mm >> 2) & 3, rr2 = mm & 3;
      int lc = (mb_ & 1) * 4 + qq;          // logical 8-key chunk
      int jj = (mb_ >> 1) * 4 + rr2;        // slot within chunk
      int basen = m0_ + jj;
#pragma unroll
      for (int mb = 0; mb < 8; ++mb)
#pragma unroll
        for (int r = 0; r < 4; ++r) {
          int d = (h * 8 + mb) * 16 + quad * 4 + r;
          ob[(size_t)d * NSP + basen + ((lc ^ (d & 7)) << 3)] =
              f2bf(acc[mb][r] + bias[d]);
        }
    } else {  // q/k: transpose via Fo -> [n][c] b128 stores, chunk-swizzled
      float sc = (op == 0) ? ATTN_SCALE : 1.f;
      int nl = wr * 16 + l16;
#pragma unroll
      for (int mb = 0; mb < 8; ++mb)
#pragma unroll
        for (int r = 0; r < 4; ++r) {
          int d = (h * 8 + mb) * 16 + quad * 4 + r;
          Fo[nl * 264 + d] = f2bf((acc[mb][r] + bias[d]) * sc);
        }
      __syncthreads();
      short* ob = ((op == 0) ? qo : ko) + (size_t)b * NSP * CCH;
      {
        int row = tid >> 3, seg = tid & 7, r7 = row & 7;  // row 0..31
        short* dst = ob + (size_t)(n0 + row) * CCH + seg * 32;
#pragma unroll
        for (int i = 0; i < 4; ++i) {
          int xch = seg * 4 + i;
          int cs = (xch & 24) | ((xch & 7) ^ r7);  // source chunk for slot xch
          *(bf16x8*)(dst + i * 8) = *(bf16x8*)(Fo + row * 264 + cs * 8);
        }
      }
      __syncthreads();
    }
  }
}

// ------ flash attention: 8 waves x 32 q/wave, 256 q/block, KSPLIT=4 --------
// 2 waves/SIMD with full 256-reg budget. Each K/V ds_read feeds 2 MFMAs.
// K,V double-buffered, ONE barrier per tile; DMA(t+1) overlaps tile t.
__global__ __launch_bounds__(512, 1) void attn_kernel(
    const short* __restrict__ q, const short* __restrict__ k,
    const short* __restrict__ v, short* __restrict__ po,
    float* __restrict__ pm, float* __restrict__ pl) {
  __shared__ __align__(16) unsigned char smem[131072];  // 128 KB
  short* Ks0 = (short*)smem;             // K even tiles
  short* Ks1 = (short*)(smem + 32768);   // K odd tiles
  short* Vs0 = (short*)(smem + 65536);   // V even tiles
  short* Vs1 = (short*)(smem + 98304);   // V odd tiles
  short* Fo  = (short*)smem;             // epilogue [64 n][264 c] bf16

  int bx = blockIdx.x;
  int b = bx & 3;
  int n0 = ((bx >> 2) & 15) << 8;   // 256-query block
  int kh = bx >> 6;                 // key quarter (0..3)
  const short* qb = q + (size_t)b * NSP * CCH;
  const short* kb = k + (size_t)b * NSP * CCH;
  const char*  vbB = (const char*)(v + (size_t)b * CCH * NSP);
  int tid = threadIdx.x;
  int w = tid >> 6, lane = tid & 63, quad = lane >> 4, l16 = lane & 15;
  int mbase = kh * TILES_PER_PART * 64;

  // ---- stage ALL 256 Q rows (128 KB) across the 4 buffers; extract ----
#pragma unroll
  for (int i = 0; i < 16; ++i) {
    int off = tid * 16 + i * 8192;
    dma16((const char*)(qb + (size_t)n0 * CCH) + off, (char*)smem + off);
  }
  __syncthreads();
  bf16x8 a_q[2][8];
#pragma unroll
  for (int qh = 0; qh < 2; ++qh) {
    int row = w * 32 + qh * 16 + l16;   // 0..255
#pragma unroll
    for (int kc = 0; kc < 8; ++kc)
      a_q[qh][kc] = *(bf16x8*)((short*)smem + row * 256 +
                               (((kc * 4 + quad) ^ (row & 7)) * 8));
  }
  __syncthreads();

  // ---- prologue: K0->Ks0, V0->Vs0 ----
#pragma unroll
  for (int i = 0; i < 4; ++i) {
    int off = tid * 16 + i * 8192;
    dma16((const char*)(kb + (size_t)mbase * CCH) + off, (char*)Ks0 + off);
    int c = off >> 7, inrow = off & 127;
    dma16(vbB + (size_t)c * (NSP * 2) + (size_t)mbase * 2 + inrow,
          (char*)Vs0 + off);
  }

  f32x4 accO[16][2];  // ch = cb*16 + quad*4 + r, query = w*32 + qh*16 + l16
#pragma unroll
  for (int cb = 0; cb < 16; ++cb)
#pragma unroll
    for (int qh = 0; qh < 2; ++qh) accO[cb][qh] = (f32x4){0.f, 0.f, 0.f, 0.f};
  float m_run[2] = {-1e30f, -1e30f}, l_run[2] = {0.f, 0.f};
  int pc0 = quad ^ (l16 & 7);        // V chunk for key-group 0 (loop-invariant)
  int pc1 = (4 + quad) ^ (l16 & 7);  // key-group 1

#pragma unroll 1
  for (int t = 0; t < TILES_PER_PART; ++t) {
    __syncthreads();  // drains DMAs into buf[t&1]; buf[(t+1)&1] readers done
    short* Kr = (t & 1) ? Ks1 : Ks0;
    short* Vr = (t & 1) ? Vs1 : Vs0;
    if (t + 1 < TILES_PER_PART) {   // DMA(t+1) overlaps all of tile t
      short* Kd = (t & 1) ? Ks0 : Ks1;
      short* Vd = (t & 1) ? Vs0 : Vs1;
      int m0 = mbase + (t + 1) * 64;
      const char* kp = (const char*)(kb + (size_t)m0 * CCH);
#pragma unroll
      for (int i = 0; i < 4; ++i) {
        int off = tid * 16 + i * 8192;
        dma16(kp + off, (char*)Kd + off);
        int c = off >> 7, inrow = off & 127;
        dma16(vbB + (size_t)c * (NSP * 2) + (size_t)m0 * 2 + inrow,
              (char*)Vd + off);
      }
    }
    // ---- S^T = K Q^T : each kf read feeds 2 MFMAs ----
    f32x4 s[4][2];
#pragma unroll
    for (int mb = 0; mb < 4; ++mb)
#pragma unroll
      for (int qh = 0; qh < 2; ++qh) s[mb][qh] = (f32x4){0.f, 0.f, 0.f, 0.f};
    __builtin_amdgcn_s_setprio(1);
#pragma unroll
    for (int kc = 0; kc < 8; ++kc) {
#pragma unroll
      for (int mb = 0; mb < 4; ++mb) {
        int row = mb * 16 + l16;
        bf16x8 kf = *(bf16x8*)(Kr + row * 256 + (((kc * 4 + quad) ^ (row & 7)) * 8));
#pragma unroll
        for (int qh = 0; qh < 2; ++qh)
          s[mb][qh] = __builtin_amdgcn_mfma_f32_16x16x32_bf16(
              kf, a_q[qh][kc], s[mb][qh], 0, 0, 0);
      }
    }
    __builtin_amdgcn_s_setprio(0);
    // ---- online softmax: per-lane scalar stats, 2 query-halves ----
    float mx[2];
#pragma unroll
    for (int qh = 0; qh < 2; ++qh) {
      float m = -1e30f;
#pragma unroll
      for (int mb = 0; mb < 4; ++mb)
#pragma unroll
        for (int r = 0; r < 4; ++r) m = fmaxf(m, s[mb][qh][r]);
      m = fmaxf(m, __shfl_xor(m, 16));
      m = fmaxf(m, __shfl_xor(m, 32));
      mx[qh] = m;
    }
    bool grow = (mx[0] - m_run[0] > 8.f) || (mx[1] - m_run[1] > 8.f);
    if (__any(grow)) {               // T13: rescale only when max grows >8
#pragma unroll
      for (int qh = 0; qh < 2; ++qh) {
        float mnew = fmaxf(m_run[qh], mx[qh]);
        float alpha = __expf(m_run[qh] - mnew);
#pragma unroll
        for (int cb = 0; cb < 16; ++cb) accO[cb][qh] *= alpha;
        l_run[qh] *= alpha;
        m_run[qh] = mnew;
      }
    }
#pragma unroll
    for (int qh = 0; qh < 2; ++qh) {
      float ls = 0.f;
#pragma unroll
      for (int mb = 0; mb < 4; ++mb)
#pragma unroll
        for (int r = 0; r < 4; ++r) {
          float p = __expf(s[mb][qh][r] - m_run[qh]);   // bounded by e^8
          ls += p;
          s[mb][qh][r] = p;
        }
      ls += __shfl_xor(ls, 16);
      ls += __shfl_xor(ls, 32);
      l_run[qh] += ls;
    }
    // ---- pack P into 16x16x32 B-frags (V key-permutation makes it direct) --
    union { unsigned u[4]; bf16x8 v; } pw0[2], pw1[2];
#pragma unroll
    for (int qh = 0; qh < 2; ++qh) {
      pw0[qh].u[0] = cvt_pk_bf16(s[0][qh][0], s[0][qh][1]);
      pw0[qh].u[1] = cvt_pk_bf16(s[0][qh][2], s[0][qh][3]);
      pw0[qh].u[2] = cvt_pk_bf16(s[2][qh][0], s[2][qh][1]);
      pw0[qh].u[3] = cvt_pk_bf16(s[2][qh][2], s[2][qh][3]);
      pw1[qh].u[0] = cvt_pk_bf16(s[1][qh][0], s[1][qh][1]);
      pw1[qh].u[1] = cvt_pk_bf16(s[1][qh][2], s[1][qh][3]);
      pw1[qh].u[2] = cvt_pk_bf16(s[3][qh][0], s[3][qh][1]);
      pw1[qh].u[3] = cvt_pk_bf16(s[3][qh][2], s[3][qh][3]);
    }
    // ---- O^T += V P^T : each vf read feeds 2 MFMAs ----
    __builtin_amdgcn_s_setprio(1);
#pragma unroll
    for (int cb = 0; cb < 16; ++cb) {
      bf16x8 vf = *(bf16x8*)(Vr + (cb * 16 + l16) * 64 + pc0 * 8);
#pragma unroll
      for (int qh = 0; qh < 2; ++qh)
        accO[cb][qh] = __builtin_amdgcn_mfma_f32_16x16x32_bf16(
            vf, pw0[qh].v, accO[cb][qh], 0, 0, 0);
    }
#pragma unroll
    for (int cb = 0; cb < 16; ++cb) {
      bf16x8 vf = *(bf16x8*)(Vr + (cb * 16 + l16) * 64 + pc1 * 8);
#pragma unroll
      for (int qh = 0; qh < 2; ++qh)
        accO[cb][qh] = __builtin_amdgcn_mfma_f32_16x16x32_bf16(
            vf, pw1[qh].v, accO[cb][qh], 0, 0, 0);
    }
    __builtin_amdgcn_s_setprio(0);
  }
  // ---- stats ----
  size_t sbase = ((size_t)kh * BB + b) * NSP + n0;
  if (quad == 0) {
#pragma unroll
    for (int qh = 0; qh < 2; ++qh) {
      pm[sbase + w * 32 + qh * 16 + l16] = m_run[qh];
      pl[sbase + w * 32 + qh * 16 + l16] = l_run[qh];
    }
  }
  // ---- epilogue: normalized bf16 O -> po [kh][b][ch][n][8] chunk-major ----
  short* ob = po + ((size_t)kh * BB + b) * NSP * CCH;
#pragma unroll
  for (int p = 0; p < 4; ++p) {
    __syncthreads();
    if ((w >> 1) == p) {
#pragma unroll
      for (int qh = 0; qh < 2; ++qh) {
        int nloc = (w & 1) * 32 + qh * 16 + l16;
        float linv = 1.f / l_run[qh];
#pragma unroll
        for (int cb = 0; cb < 16; ++cb)
#pragma unroll
          for (int r = 0; r < 4; ++r)
            Fo[nloc * 264 + cb * 16 + quad * 4 + r] =
                f2bf(accO[cb][qh][r] * linv);
      }
    }
    __syncthreads();
    int row = tid >> 3, seg = tid & 7;
    int n = n0 + p * 64 + row;
#pragma unroll
    for (int i = 0; i < 4; ++i) {
      int ch = seg * 4 + i;
      *(bf16x8*)(ob + ((size_t)ch * NSP + n) * 8) =
          *(bf16x8*)(Fo + row * 264 + ch * 8);
    }
  }
}

// ------- proj: frag-direct MFMA, KSPLIT-way merge, chunk-major poT reads ---
__global__ __launch_bounds__(256) void proj_kernel(
    const short* __restrict__ po, const float* __restrict__ pm,
    const float* __restrict__ pl, const short* __restrict__ wpt,
    const float* __restrict__ bp, const float* __restrict__ x,
    float* __restrict__ out) {
  int n0 = blockIdx.x * 32;
  int dh = blockIdx.y * 128;
  int b = blockIdx.z;
  int tid = threadIdx.x;
  int w = tid >> 6, lane = tid & 63, quad = lane >> 4, l16 = lane & 15;
  int ng = w & 1, hq = w >> 1;
  int n = n0 + ng * 16 + l16;
  int dbase = dh + hq * 64;

  float wgt[KSPLIT];
  {
    float m[KSPLIT];
    float M = -1e30f;
#pragma unroll
    for (int s = 0; s < KSPLIT; ++s) {
      m[s] = pm[((size_t)s * BB + b) * NSP + n];
      M = fmaxf(M, m[s]);
    }
    float wsum = 0.f;
#pragma unroll
    for (int s = 0; s < KSPLIT; ++s) {
      wgt[s] = __expf(m[s] - M) * pl[((size_t)s * BB + b) * NSP + n];
      wsum += wgt[s];
    }
    float linv = 1.f / wsum;
#pragma unroll
    for (int s = 0; s < KSPLIT; ++s) wgt[s] *= linv;
  }

  f32x4 acc[4];
#pragma unroll
  for (int mb = 0; mb < 4; ++mb) acc[mb] = (f32x4){0.f, 0.f, 0.f, 0.f};

#pragma unroll 2
  for (int kc = 0; kc < 8; ++kc) {
    int coff = kc * 32 + quad * 8;
    int ch = kc * 4 + quad;   // c-chunk index for chunk-major poT
    float e[8];
#pragma unroll
    for (int i = 0; i < 8; ++i) e[i] = 0.f;
#pragma unroll
    for (int s = 0; s < KSPLIT; ++s) {
      bf16x8 f = *(const bf16x8*)(po + ((size_t)s * BB + b) * NSP * CCH +
                                  ((size_t)ch * NSP + n) * 8);
#pragma unroll
      for (int i = 0; i < 8; ++i) e[i] += wgt[s] * bf2f(f[i]);
    }
    bf16x8 bm;
#pragma unroll
    for (int i = 0; i < 8; ++i) bm[i] = f2bf(e[i]);
#pragma unroll
    for (int mb = 0; mb < 4; ++mb) {
      bf16x8 af = *(const bf16x8*)(wpt + (size_t)(dbase + mb * 16 + l16) * CCH + coff);
      acc[mb] = __builtin_amdgcn_mfma_f32_16x16x32_bf16(af, bm, acc[mb], 0, 0, 0);
    }
  }
#pragma unroll
  for (int mb = 0; mb < 4; ++mb) {
#pragma unroll
    for (int r = 0; r < 4; ++r) {
      int d = dbase + mb * 16 + quad * 4 + r;
      size_t off = ((size_t)b * CCH + d) * NSP + n;
      out[off] = (acc[mb][r] + bp[d] + x[off]) * RSQRT2;
    }
  }
}

extern "C" void kernel_launch(void* const* d_in, const int* in_sizes, int n_in,
                              void* d_out, int out_size, void* d_ws, size_t ws_size,
                              hipStream_t stream) {
  const float* x  = (const float*)d_in[0];
  const float* gw = (const float*)d_in[1];
  const float* gb = (const float*)d_in[2];
  const float* Wq = (const float*)d_in[3];
  const float* bq = (const float*)d_in[4];
  const float* Wk = (const float*)d_in[5];
  const float* bk = (const float*)d_in[6];
  const float* Wv = (const float*)d_in[7];
  const float* bv = (const float*)d_in[8];
  const float* Wp = (const float*)d_in[9];
  const float* bp = (const float*)d_in[10];
  float* out = (float*)d_out;

  const size_t SZ = (size_t)BB * CCH * NSP;  // 4.19M elems
  short* qb  = (short*)d_ws;                 // bf16 [b][n][c] swizzled, scaled
  short* kb  = qb + SZ;                      // bf16 [b][n][c] swizzled
  short* vb  = kb + SZ;                      // bf16 [b][c][n] permuted
  short* poT = vb + SZ;                      // bf16 [KSPLIT][b][ch][n][8]
  float* pm  = (float*)(poT + (size_t)KSPLIT * SZ);  // [KSPLIT][b][n]
  float* pl  = pm + (size_t)KSPLIT * BB * NSP;
  float* stats = pl + (size_t)KSPLIT * BB * NSP;     // [b][32][2 half][2] raw
  short* wts = (short*)(stats + BB * 128);           // bf16 [4][256][256]
  short* wqt = wts;
  short* wkt = wts + (size_t)CCH * CCH;
  short* wvt = wts + (size_t)2 * CCH * CCH;
  short* wpt = wts + (size_t)3 * CCH * CCH;

  prep_all<<<dim3(320), dim3(256), 0, stream>>>(x, Wq, Wk, Wv, Wp, stats, wts);
  qkvg_kernel<<<dim3(512), dim3(256), 0, stream>>>(
      x, stats, gw, gb, wqt, wkt, wvt, bq, bk, bv, qb, kb, vb);
  attn_kernel<<<dim3(BB * 16 * KSPLIT), dim3(512), 0, stream>>>(
      qb, kb, vb, poT, pm, pl);
  proj_kernel<<<dim3(128, 2, BB), dim3(256), 0, stream>>>(
      poT, pm, pl, wpt, bp, x, out);
}

// Round 13
// 249.371 us; speedup vs baseline: 1.0935x; 1.0935x over previous
//
#include <hip/hip_runtime.h>
#include <math.h>

// AttnBlock: GroupNorm(32) -> q,k,v 1x1 -> spatial attention -> proj -> resid.
// Round 22: attn reverted to R20/round-11 exact (98.0us proven; R21's 32q/wave
// spilled AGAIN -- mechanism now closed: accO needs 128 AGPRs, so VALU state
// must fit 128 arch VGPRs; 32q needs ~140 -> 16q/wave is the only fit).
// Non-attn surgery (the class that has paid every time):
// - qkvg: q+k projections fused -- one mb/kc loop (shared a_h reads), one
//   dual-Fo epilogue with ONE barrier (was 4 across two serial ops).
// - proj: KSPLIT merge moved from VALU (bf2f/fma/f2bf per kc) into MFMA:
//   acc_s = W @ po_s per stream, final per-lane combine wgt0*acc0+wgt1*acc1
//   (merge is linear). ~500 VALU ops/iter -> 2 loads + 8 MFMA.

#define BB 4
#define CCH 256
#define NSP 4096
#define EPSV 1e-5f
#define ATTN_SCALE 0.0625f  // 256^-0.5
#define RSQRT2 0.70710678118654752440f
#define KSPLIT 2
#define TILES_PER_PART 32   // 4096 / 64 / KSPLIT

typedef __attribute__((ext_vector_type(8))) short bf16x8;
typedef __attribute__((ext_vector_type(4))) float f32x4;

typedef __attribute__((address_space(1))) void gvoid;
typedef __attribute__((address_space(3))) void lvoid;
__device__ __forceinline__ void dma16(const void* g, void* l) {
  __builtin_amdgcn_global_load_lds((gvoid*)g, (lvoid*)l, 16, 0, 0);
}

__device__ __forceinline__ short f2bf(float f) {
  union { float f; unsigned u; } a; a.f = f;
  unsigned r = a.u + 0x7fffu + ((a.u >> 16) & 1u);  // RTN-even
  return (short)(r >> 16);
}
__device__ __forceinline__ float bf2f(short s) {
  union { unsigned u; float f; } a;
  a.u = ((unsigned)(unsigned short)s) << 16;
  return a.f;
}
__device__ __forceinline__ unsigned cvt_pk_bf16(float lo, float hi) {
  unsigned r;
  asm("v_cvt_pk_bf16_f32 %0, %1, %2" : "=v"(r) : "v"(lo), "v"(hi));
  return r;
}

// ---- prep_all: GN partial stats (blocks 0..255) + W transpose (256..319) ---
__global__ __launch_bounds__(256) void prep_all(
    const float* __restrict__ x,
    const float* __restrict__ Wq, const float* __restrict__ Wk,
    const float* __restrict__ Wv, const float* __restrict__ Wp,
    float* __restrict__ stats, short* __restrict__ wts) {
  __shared__ float T[64][65];
  int bid = blockIdx.x;
  int tid = threadIdx.x;
  if (bid < 256) {
    int b = bid >> 6, g = (bid >> 1) & 31, h = bid & 1;
    size_t base = ((size_t)b * CCH + (size_t)g * 8 + (size_t)h * 4) * NSP;
    const float4* xv = (const float4*)(x + base);
    float s = 0.f, ss = 0.f;
    for (int i = tid; i < 4096; i += 256) {
      float4 v = xv[i];
      s += (v.x + v.y) + (v.z + v.w);
      ss += (v.x * v.x + v.y * v.y) + (v.z * v.z + v.w * v.w);
    }
#pragma unroll
    for (int off = 32; off > 0; off >>= 1) {
      s += __shfl_down(s, off, 64);
      ss += __shfl_down(ss, off, 64);
    }
    int wv = tid >> 6;
    if ((tid & 63) == 0) { T[0][wv] = s; T[0][4 + wv] = ss; }
    __syncthreads();
    if (tid == 0) {
      float S = T[0][0] + T[0][1] + T[0][2] + T[0][3];
      float SS = T[0][4] + T[0][5] + T[0][6] + T[0][7];
      stats[((b * 32 + g) * 2 + h) * 2 + 0] = S;
      stats[((b * 32 + g) * 2 + h) * 2 + 1] = SS;
    }
  } else {
    int wid = bid - 256;
    int c0 = (wid & 3) * 64, d0 = ((wid >> 2) & 3) * 64;
    int wz = wid >> 4;
    const float* W = (wz == 0) ? Wq : (wz == 1) ? Wk : (wz == 2) ? Wv : Wp;
    short* wt = wts + (size_t)wz * CCH * CCH;
#pragma unroll
    for (int i = 0; i < 16; ++i) {
      int idx = tid + 256 * i;
      int row = idx >> 6, col = idx & 63;
      T[row][col] = W[(size_t)(c0 + row) * CCH + d0 + col];
    }
    __syncthreads();
#pragma unroll
    for (int i = 0; i < 16; ++i) {
      int idx = tid + 256 * i;
      int dr = idx >> 6, cc = idx & 63;
      wt[(size_t)(d0 + dr) * CCH + c0 + cc] = f2bf(T[cc][dr]);
    }
  }
}

// ------- qkvg: fused GN-apply + q,k,v projections via bf16 MFMA -----------
// n-block = 32, grid 512 = 2 blocks/CU. 256 threads / 4 waves:
// wave w: wr = w&1 (n-group of 16), h = w>>1 (d-half of 128).
// q+k computed in ONE loop (shared a_h), dual-Fo epilogue with one barrier.
__global__ __launch_bounds__(256) void qkvg_kernel(
    const float* __restrict__ x, const float* __restrict__ stats,
    const float* __restrict__ gw, const float* __restrict__ gb,
    const short* __restrict__ wqt, const short* __restrict__ wkt,
    const short* __restrict__ wvt,
    const float* __restrict__ bq, const float* __restrict__ bk,
    const float* __restrict__ bv,
    short* __restrict__ qo, short* __restrict__ ko, short* __restrict__ vo) {
  __shared__ __align__(16) unsigned char smem[35840];
  float* aco = (float*)smem;                      // 256 f32
  float* bco = aco + 256;                         // 256 f32
  float (*Ts)[33] = (float(*)[33])(smem + 2048);  // 64 x 33 fp32 (8448 B)
  short* Hs = (short*)(smem + 10496);             // [32 n][256 c] swizzled
  short* Foq = (short*)(smem + 2048);             // [32 n][264] bf16 (16896 B)
  short* Fok = (short*)(smem + 18944);            // [32 n][264] bf16

  int bx = blockIdx.x;
  int b = bx & 3, n0 = (bx >> 2) * 32;
  int tid = threadIdx.x;
  {  // per-channel scale/shift (combine 2 GN partials)
    int g = tid >> 3;
    const float* sp = stats + (size_t)(b * 32 + g) * 4;
    float S = sp[0] + sp[2], SS = sp[1] + sp[3];
    float mean = S * (1.f / 32768.f);
    float var = SS * (1.f / 32768.f) - mean * mean;
    float rstd = rsqrtf(var + EPSV);
    float a = gw[tid] * rstd;
    aco[tid] = a;
    bco[tid] = gb[tid] - mean * a;
  }
  __syncthreads();
  const float* xb = x + (size_t)b * CCH * NSP;
  // ---- 4 passes: load x chunk (64c x 32n), normalize, transpose -> Hs ----
  for (int p = 0; p < 4; ++p) {
    int c0 = p * 64;
#pragma unroll
    for (int i = 0; i < 2; ++i) {
      int crow = (tid >> 3) + i * 32;
      int c = c0 + crow;
      float4 v = *(const float4*)&xb[(size_t)c * NSP + n0 + (tid & 7) * 4];
      float a = aco[c], bb = bco[c];
      v.x = v.x * a + bb; v.y = v.y * a + bb;
      v.z = v.z * a + bb; v.w = v.w * a + bb;
      *(float4*)&Ts[crow][(tid & 7) * 4] = v;   // Ts[c_local][n_local]
    }
    __syncthreads();
    {
      int n = tid >> 3, seg = tid & 7;
      int cb = seg * 8;
      bf16x8 r;
#pragma unroll
      for (int j = 0; j < 8; ++j) r[j] = f2bf(Ts[cb + j][n]);
      int chunk = p * 8 + seg;
      *(bf16x8*)(Hs + n * 256 + ((chunk ^ (n & 7)) * 8)) = r;
    }
    __syncthreads();
  }
  // ---- extract B-frags (rows = this wave's 16 n; shared across h) ----
  int w = tid >> 6, lane = tid & 63, quad = lane >> 4, l16 = lane & 15;
  int wr = w & 1, h = w >> 1;  // n-group, d-half
  bf16x8 a_h[8];
  {
    int row = wr * 16 + l16;
#pragma unroll
    for (int kc = 0; kc < 8; ++kc)
      a_h[kc] = *(bf16x8*)(Hs + row * 256 + (((kc * 4 + quad) ^ (row & 7)) * 8));
  }
  __syncthreads();  // all waves extracted; Hs region reusable (Foq/Fok)
  int n = n0 + wr * 16 + l16;
  // ---- q + k fused: one mb/kc loop, shared a_h ----
  {
    f32x4 accq[8], acck[8];
#pragma unroll
    for (int mb = 0; mb < 8; ++mb) {
      accq[mb] = (f32x4){0.f, 0.f, 0.f, 0.f};
      acck[mb] = (f32x4){0.f, 0.f, 0.f, 0.f};
    }
#pragma unroll 2
    for (int mb = 0; mb < 8; ++mb) {
      size_t wo = (size_t)((h * 8 + mb) * 16 + l16) * CCH + quad * 8;
      const short* wpq = wqt + wo;
      const short* wpk = wkt + wo;
#pragma unroll
      for (int kc = 0; kc < 8; ++kc) {
        bf16x8 afq = *(const bf16x8*)(wpq + kc * 32);
        bf16x8 afk = *(const bf16x8*)(wpk + kc * 32);
        accq[mb] = __builtin_amdgcn_mfma_f32_16x16x32_bf16(afq, a_h[kc], accq[mb], 0, 0, 0);
        acck[mb] = __builtin_amdgcn_mfma_f32_16x16x32_bf16(afk, a_h[kc], acck[mb], 0, 0, 0);
      }
    }
    int nl = wr * 16 + l16;
#pragma unroll
    for (int mb = 0; mb < 8; ++mb)
#pragma unroll
      for (int r = 0; r < 4; ++r) {
        int d = (h * 8 + mb) * 16 + quad * 4 + r;
        Foq[nl * 264 + d] = f2bf((accq[mb][r] + bq[d]) * ATTN_SCALE);
        Fok[nl * 264 + d] = f2bf(acck[mb][r] + bk[d]);
      }
    __syncthreads();
    short* obq = qo + (size_t)b * NSP * CCH;
    short* obk = ko + (size_t)b * NSP * CCH;
    int row = tid >> 3, seg = tid & 7, r7 = row & 7;  // row 0..31
    short* dq = obq + (size_t)(n0 + row) * CCH + seg * 32;
    short* dk = obk + (size_t)(n0 + row) * CCH + seg * 32;
#pragma unroll
    for (int i = 0; i < 4; ++i) {
      int xch = seg * 4 + i;
      int cs = (xch & 24) | ((xch & 7) ^ r7);  // source chunk for slot xch
      *(bf16x8*)(dq + i * 8) = *(bf16x8*)(Foq + row * 264 + cs * 8);
      *(bf16x8*)(dk + i * 8) = *(bf16x8*)(Fok + row * 264 + cs * 8);
    }
  }
  // ---- v: direct scatter stores (no LDS) ----
  {
    f32x4 acc[8];
#pragma unroll
    for (int mb = 0; mb < 8; ++mb) acc[mb] = (f32x4){0.f, 0.f, 0.f, 0.f};
#pragma unroll 4
    for (int mb = 0; mb < 8; ++mb) {
      const short* wp = wvt + (size_t)((h * 8 + mb) * 16 + l16) * CCH + quad * 8;
#pragma unroll
      for (int kc = 0; kc < 8; ++kc) {
        bf16x8 af = *(const bf16x8*)(wp + kc * 32);
        acc[mb] = __builtin_amdgcn_mfma_f32_16x16x32_bf16(af, a_h[kc], acc[mb], 0, 0, 0);
      }
    }
    short* ob = vo + (size_t)b * CCH * NSP;
    int mm = n & 63, m0_ = n & ~63;
    int mb_ = mm >> 4, qq = (mm >> 2) & 3, rr2 = mm & 3;
    int lc = (mb_ & 1) * 4 + qq;          // logical 8-key chunk
    int jj = (mb_ >> 1) * 4 + rr2;        // slot within chunk
    int basen = m0_ + jj;
#pragma unroll
    for (int mb = 0; mb < 8; ++mb)
#pragma unroll
      for (int r = 0; r < 4; ++r) {
        int d = (h * 8 + mb) * 16 + quad * 4 + r;
        ob[(size_t)d * NSP + basen + ((lc ^ (d & 7)) << 3)] =
            f2bf(acc[mb][r] + bv[d]);
      }
  }
}

// ------ flash attention: 8 waves, 16 q/wave, 128 q/block, pipelined --------
// R13/round-4 structure. K,V double-buffered (128 KiB LDS); one barrier per
// tile; QK(t+1) overlaps softmax(t)+PV(t). Epilogue writes poT chunk-major:
// po2[kh][b][ch][n][8] (ch = c/8) so proj's reads are contiguous.
__global__ __launch_bounds__(512, 1) void attn_kernel(
    const short* __restrict__ q, const short* __restrict__ k,
    const short* __restrict__ v, short* __restrict__ po,
    float* __restrict__ pm, float* __restrict__ pl) {
  __shared__ __align__(16) unsigned char smem[131072];  // 128 KB
  short* Ks0 = (short*)smem;             // K even tiles / Q stage
  short* Ks1 = (short*)(smem + 32768);   // K odd tiles
  short* Vs0 = (short*)(smem + 65536);   // V even tiles
  short* Vs1 = (short*)(smem + 98304);   // V odd tiles
  short* Fo  = (short*)smem;             // epilogue [64 n][264 c] bf16

  int bx = blockIdx.x;
  int b = bx & 3;
  int n0 = ((bx >> 2) & 31) << 7;   // 128-query block
  int kh = bx >> 7;                 // key half
  const short* qb = q + (size_t)b * NSP * CCH;
  const short* kb = k + (size_t)b * NSP * CCH;
  const char*  vbB = (const char*)(v + (size_t)b * CCH * NSP);
  int tid = threadIdx.x;
  int w = tid >> 6, lane = tid & 63, quad = lane >> 4, l16 = lane & 15;
  int mbase = kh * TILES_PER_PART * 64;

  // ---- stage Q in 2 passes of 64 rows through Ks0; extract B-frags ----
  bf16x8 a_q[8];
#pragma unroll
  for (int p = 0; p < 2; ++p) {
#pragma unroll
    for (int i = 0; i < 4; ++i) {
      int off = tid * 16 + i * 8192;
      dma16((const char*)(qb + (size_t)(n0 + p * 64) * CCH) + off,
            (char*)Ks0 + off);
    }
    __syncthreads();
    if ((w >> 2) == p) {
      int row = (w & 3) * 16 + l16;
#pragma unroll
      for (int kc = 0; kc < 8; ++kc)
        a_q[kc] = *(bf16x8*)(Ks0 + row * 256 + (((kc * 4 + quad) ^ (row & 7)) * 8));
    }
    __syncthreads();
  }

  // ---- prologue: K0->Ks0, V0->Vs0; drain; K1->Ks1; QK(0) ----
#pragma unroll
  for (int i = 0; i < 4; ++i) {
    int off = tid * 16 + i * 8192;
    dma16((const char*)(kb + (size_t)mbase * CCH) + off, (char*)Ks0 + off);
    int c = off >> 7, inrow = off & 127;
    dma16(vbB + (size_t)c * (NSP * 2) + (size_t)mbase * 2 + inrow,
          (char*)Vs0 + off);
  }
  __syncthreads();
#pragma unroll
  for (int i = 0; i < 4; ++i) {
    int off = tid * 16 + i * 8192;
    dma16((const char*)(kb + (size_t)(mbase + 64) * CCH) + off,
          (char*)Ks1 + off);
  }
  f32x4 s_prev[4];
#pragma unroll
  for (int mb = 0; mb < 4; ++mb) s_prev[mb] = (f32x4){0.f, 0.f, 0.f, 0.f};
  __builtin_amdgcn_s_setprio(1);
#pragma unroll
  for (int kc = 0; kc < 8; ++kc) {
#pragma unroll
    for (int mb = 0; mb < 4; ++mb) {
      int row = mb * 16 + l16;
      bf16x8 kf = *(bf16x8*)(Ks0 + row * 256 + (((kc * 4 + quad) ^ (row & 7)) * 8));
      s_prev[mb] = __builtin_amdgcn_mfma_f32_16x16x32_bf16(kf, a_q[kc], s_prev[mb], 0, 0, 0);
    }
  }
  __builtin_amdgcn_s_setprio(0);

  f32x4 accO[16];  // O^T C-layout: ch = cb*16 + quad*4 + r, query = w*16+l16
#pragma unroll
  for (int cb = 0; cb < 16; ++cb) accO[cb] = (f32x4){0.f, 0.f, 0.f, 0.f};
  float m_run = -1e30f, l_run = 0.f;
  int pc0 = quad ^ (l16 & 7);        // V chunk for key-group 0 (loop-invariant)
  int pc1 = (4 + quad) ^ (l16 & 7);  // key-group 1

#pragma unroll 1
  for (int t = 0; t < TILES_PER_PART; ++t) {
    __syncthreads();  // DMA(issued last iter) complete; buffers' readers done
    short* Kd = (t & 1) ? Ks1 : Ks0;   // dest for K(t+2)
    short* Kr = (t & 1) ? Ks0 : Ks1;   // source for QK(t+1)
    short* Vd = (t & 1) ? Vs0 : Vs1;   // dest for V(t+1)
    short* Vr = (t & 1) ? Vs1 : Vs0;   // source for PV(t)
    if (t + 2 < TILES_PER_PART) {      // K-DMA(t+2): last read by QK(t) prev iter
      const char* kp = (const char*)(kb + (size_t)(mbase + (t + 2) * 64) * CCH);
#pragma unroll
      for (int i = 0; i < 4; ++i) {
        int off = tid * 16 + i * 8192;
        dma16(kp + off, (char*)Kd + off);
      }
    }
    if (t + 1 < TILES_PER_PART) {      // V-DMA(t+1): last read by PV(t-1)
      int m0 = mbase + (t + 1) * 64;
#pragma unroll
      for (int i = 0; i < 4; ++i) {
        int off = tid * 16 + i * 8192;
        int c = off >> 7, inrow = off & 127;
        dma16(vbB + (size_t)c * (NSP * 2) + (size_t)m0 * 2 + inrow,
              (char*)Vd + off);
      }
    }
    // ---- QK(t+1): independent MFMA stream, fills pipe under softmax(t) ----
    f32x4 sn[4];
#pragma unroll
    for (int mb = 0; mb < 4; ++mb) sn[mb] = (f32x4){0.f, 0.f, 0.f, 0.f};
    if (t + 1 < TILES_PER_PART) {
      __builtin_amdgcn_s_setprio(1);
#pragma unroll
      for (int kc = 0; kc < 8; ++kc) {
#pragma unroll
        for (int mb = 0; mb < 4; ++mb) {
          int row = mb * 16 + l16;
          bf16x8 kf = *(bf16x8*)(Kr + row * 256 + (((kc * 4 + quad) ^ (row & 7)) * 8));
          sn[mb] = __builtin_amdgcn_mfma_f32_16x16x32_bf16(kf, a_q[kc], sn[mb], 0, 0, 0);
        }
      }
      __builtin_amdgcn_s_setprio(0);
    }
    // ---- online softmax(t) on s_prev: per-lane scalar stats ----
    float mx = -1e30f;
#pragma unroll
    for (int mb = 0; mb < 4; ++mb)
#pragma unroll
      for (int r = 0; r < 4; ++r) mx = fmaxf(mx, s_prev[mb][r]);
    mx = fmaxf(mx, __shfl_xor(mx, 16));
    mx = fmaxf(mx, __shfl_xor(mx, 32));
    if (!__all(mx - m_run <= 8.f)) {   // T13: rescale only when max grows >8
      float mnew = fmaxf(m_run, mx);
      float alpha = __expf(m_run - mnew);
#pragma unroll
      for (int cb = 0; cb < 16; ++cb) accO[cb] *= alpha;
      l_run *= alpha;
      m_run = mnew;
    }
    float ls = 0.f;
#pragma unroll
    for (int mb = 0; mb < 4; ++mb)
#pragma unroll
      for (int r = 0; r < 4; ++r) {
        float p = __expf(s_prev[mb][r] - m_run);   // bounded by e^8
        ls += p;
        s_prev[mb][r] = p;
      }
    ls += __shfl_xor(ls, 16);
    ls += __shfl_xor(ls, 32);
    l_run += ls;
    // ---- pack P into 16x16x32 B-frags (key permutation makes this direct) --
    union { unsigned u[4]; bf16x8 v; } pw0, pw1;
    pw0.u[0] = cvt_pk_bf16(s_prev[0][0], s_prev[0][1]);
    pw0.u[1] = cvt_pk_bf16(s_prev[0][2], s_prev[0][3]);
    pw0.u[2] = cvt_pk_bf16(s_prev[2][0], s_prev[2][1]);
    pw0.u[3] = cvt_pk_bf16(s_prev[2][2], s_prev[2][3]);
    pw1.u[0] = cvt_pk_bf16(s_prev[1][0], s_prev[1][1]);
    pw1.u[1] = cvt_pk_bf16(s_prev[1][2], s_prev[1][3]);
    pw1.u[2] = cvt_pk_bf16(s_prev[3][0], s_prev[3][1]);
    pw1.u[3] = cvt_pk_bf16(s_prev[3][2], s_prev[3][3]);
    // ---- O^T += V P^T : full-rate 16x16x32, b128 V reads ----
    __builtin_amdgcn_s_setprio(1);
#pragma unroll
    for (int cb = 0; cb < 16; ++cb) {
      bf16x8 vf = *(bf16x8*)(Vr + (cb * 16 + l16) * 64 + pc0 * 8);
      accO[cb] = __builtin_amdgcn_mfma_f32_16x16x32_bf16(vf, pw0.v, accO[cb], 0, 0, 0);
    }
#pragma unroll
    for (int cb = 0; cb < 16; ++cb) {
      bf16x8 vf = *(bf16x8*)(Vr + (cb * 16 + l16) * 64 + pc1 * 8);
      accO[cb] = __builtin_amdgcn_mfma_f32_16x16x32_bf16(vf, pw1.v, accO[cb], 0, 0, 0);
    }
    __builtin_amdgcn_s_setprio(0);
    // ---- roll S ----
#pragma unroll
    for (int mb = 0; mb < 4; ++mb) s_prev[mb] = sn[mb];
  }
  // ---- stats ----
  size_t sbase = ((size_t)kh * BB + b) * NSP + n0;
  if (quad == 0) {
    pm[sbase + w * 16 + l16] = m_run;
    pl[sbase + w * 16 + l16] = l_run;
  }
  // ---- epilogue: normalized bf16 O -> po2 [kh][b][ch][n][8] chunk-major ----
  float linv = 1.f / l_run;
  short* ob = po + ((size_t)kh * BB + b) * NSP * CCH;
#pragma unroll
  for (int p = 0; p < 2; ++p) {
    __syncthreads();
    if ((w >> 2) == p) {
      int nloc = (w & 3) * 16 + l16;
#pragma unroll
      for (int cb = 0; cb < 16; ++cb)
#pragma unroll
        for (int r = 0; r < 4; ++r)
          Fo[nloc * 264 + cb * 16 + quad * 4 + r] = f2bf(accO[cb][r] * linv);
    }
    __syncthreads();
    int row = tid >> 3, seg = tid & 7;
    int n = n0 + p * 64 + row;
#pragma unroll
    for (int i = 0; i < 4; ++i) {
      int ch = seg * 4 + i;
      *(bf16x8*)(ob + ((size_t)ch * NSP + n) * 8) =
          *(bf16x8*)(Fo + row * 264 + ch * 8);
    }
  }
}

// ------- proj: dual-stream MFMA merge (linear), chunk-major poT reads ------
// 256 threads / 4 waves: wave = (ng = w&1 n-group of 16) x (hq = w>>1
// d-quarter of 64). acc_s = W @ po_s per stream; final per-lane combine.
__global__ __launch_bounds__(256) void proj_kernel(
    const short* __restrict__ po, const float* __restrict__ pm,
    const float* __restrict__ pl, const short* __restrict__ wpt,
    const float* __restrict__ bp, const float* __restrict__ x,
    float* __restrict__ out) {
  int n0 = blockIdx.x * 32;
  int dh = blockIdx.y * 128;
  int b = blockIdx.z;
  int tid = threadIdx.x;
  int w = tid >> 6, lane = tid & 63, quad = lane >> 4, l16 = lane & 15;
  int ng = w & 1, hq = w >> 1;
  int n = n0 + ng * 16 + l16;
  int dbase = dh + hq * 64;

  float wgt[KSPLIT];
  {
    float m[KSPLIT];
    float M = -1e30f;
#pragma unroll
    for (int s = 0; s < KSPLIT; ++s) {
      m[s] = pm[((size_t)s * BB + b) * NSP + n];
      M = fmaxf(M, m[s]);
    }
    float wsum = 0.f;
#pragma unroll
    for (int s = 0; s < KSPLIT; ++s) {
      wgt[s] = __expf(m[s] - M) * pl[((size_t)s * BB + b) * NSP + n];
      wsum += wgt[s];
    }
    float linv = 1.f / wsum;
#pragma unroll
    for (int s = 0; s < KSPLIT; ++s) wgt[s] *= linv;
  }

  f32x4 acc0[4], acc1[4];
#pragma unroll
  for (int mb = 0; mb < 4; ++mb) {
    acc0[mb] = (f32x4){0.f, 0.f, 0.f, 0.f};
    acc1[mb] = (f32x4){0.f, 0.f, 0.f, 0.f};
  }

#pragma unroll 2
  for (int kc = 0; kc < 8; ++kc) {
    int coff = kc * 32 + quad * 8;
    int ch = kc * 4 + quad;   // c-chunk index for chunk-major poT
    bf16x8 f0 = *(const bf16x8*)(po + ((size_t)0 * BB + b) * NSP * CCH +
                                 ((size_t)ch * NSP + n) * 8);
    bf16x8 f1 = *(const bf16x8*)(po + ((size_t)1 * BB + b) * NSP * CCH +
                                 ((size_t)ch * NSP + n) * 8);
#pragma unroll
    for (int mb = 0; mb < 4; ++mb) {
      bf16x8 af = *(const bf16x8*)(wpt + (size_t)(dbase + mb * 16 + l16) * CCH + coff);
      acc0[mb] = __builtin_amdgcn_mfma_f32_16x16x32_bf16(af, f0, acc0[mb], 0, 0, 0);
      acc1[mb] = __builtin_amdgcn_mfma_f32_16x16x32_bf16(af, f1, acc1[mb], 0, 0, 0);
    }
  }
  // wgt is per-query(n); C-layout col = lane&15 = this lane's n -> per-lane.
#pragma unroll
  for (int mb = 0; mb < 4; ++mb) {
#pragma unroll
    for (int r = 0; r < 4; ++r) {
      int d = dbase + mb * 16 + quad * 4 + r;
      size_t off = ((size_t)b * CCH + d) * NSP + n;
      float val = wgt[0] * acc0[mb][r] + wgt[1] * acc1[mb][r];
      out[off] = (val + bp[d] + x[off]) * RSQRT2;
    }
  }
}

extern "C" void kernel_launch(void* const* d_in, const int* in_sizes, int n_in,
                              void* d_out, int out_size, void* d_ws, size_t ws_size,
                              hipStream_t stream) {
  const float* x  = (const float*)d_in[0];
  const float* gw = (const float*)d_in[1];
  const float* gb = (const float*)d_in[2];
  const float* Wq = (const float*)d_in[3];
  const float* bq = (const float*)d_in[4];
  const float* Wk = (const float*)d_in[5];
  const float* bk = (const float*)d_in[6];
  const float* Wv = (const float*)d_in[7];
  const float* bv = (const float*)d_in[8];
  const float* Wp = (const float*)d_in[9];
  const float* bp = (const float*)d_in[10];
  float* out = (float*)d_out;

  const size_t SZ = (size_t)BB * CCH * NSP;  // 4.19M elems
  short* qb  = (short*)d_ws;                 // bf16 [b][n][c] swizzled, scaled
  short* kb  = qb + SZ;                      // bf16 [b][n][c] swizzled
  short* vb  = kb + SZ;                      // bf16 [b][c][n] permuted
  short* poT = vb + SZ;                      // bf16 [KSPLIT][b][ch][n][8]
  float* pm  = (float*)(poT + (size_t)KSPLIT * SZ);  // [KSPLIT][b][n]
  float* pl  = pm + (size_t)KSPLIT * BB * NSP;
  float* stats = pl + (size_t)KSPLIT * BB * NSP;     // [b][32][2 half][2] raw
  short* wts = (short*)(stats + BB * 128);           // bf16 [4][256][256]
  short* wqt = wts;
  short* wkt = wts + (size_t)CCH * CCH;
  short* wvt = wts + (size_t)2 * CCH * CCH;
  short* wpt = wts + (size_t)3 * CCH * CCH;

  prep_all<<<dim3(320), dim3(256), 0, stream>>>(x, Wq, Wk, Wv, Wp, stats, wts);
  qkvg_kernel<<<dim3(512), dim3(256), 0, stream>>>(
      x, stats, gw, gb, wqt, wkt, wvt, bq, bk, bv, qb, kb, vb);
  attn_kernel<<<dim3(BB * 32 * KSPLIT), dim3(512), 0, stream>>>(
      qb, kb, vb, poT, pm, pl);
  proj_kernel<<<dim3(128, 2, BB), dim3(256), 0, stream>>>(
      poT, pm, pl, wpt, bp, x, out);
}